// Round 2
// baseline (762.634 us; speedup 1.0000x reference)
//
#include <hip/hip_runtime.h>

#define HASH_BINS 100000
#define EMBD 64
#define BATCH 262144
#define BM 64
#define LSTR 264  // LDS activation row stride (bf16 elems); 264*2=528B breaks 32-bank alignment

typedef __attribute__((ext_vector_type(8))) short short8;
typedef __attribute__((ext_vector_type(4))) float floatx4;
typedef __attribute__((ext_vector_type(4))) unsigned short ushortx4;

static __device__ __forceinline__ unsigned short f2bf(float f) {
  unsigned u = __builtin_bit_cast(unsigned, f);
  u += 0x7fff + ((u >> 16) & 1);  // round-to-nearest-even
  return (unsigned short)(u >> 16);
}
static __device__ __forceinline__ float bf2f(unsigned short b) {
  return __builtin_bit_cast(float, ((unsigned)b) << 16);
}

// ---------------- prep: build bf16 transposed/padded weights in ws ----------------
// ws layout (bytes):
//   0      : S   fp32 [128]            (rowsum of cross_k^2)
//   512    : Kt  bf16 [128][128]       (cross_k transposed)   } contiguous => combined
//   33280  : W1t bf16 [224][128]       (W1 transposed, N-pad) } [352][128] matrix
//   90624  : W2t bf16 [256][224]       (K-pad 200->224)
//   205312 : W3t bf16 [224][256]       (N-pad 200->224)
//   320000 : W4t bf16 [128][224]       (K-pad 200->224)
// All copy segments iterate over the SOURCE layout so global reads are coalesced;
// transposed writes scatter (stores don't stall the wave).
__global__ void dfm_prep(const float* __restrict__ K, const float* __restrict__ W1,
                         const float* __restrict__ W2, const float* __restrict__ W3,
                         const float* __restrict__ W4,
                         float* __restrict__ S, unsigned short* __restrict__ Kt,
                         unsigned short* __restrict__ W1t, unsigned short* __restrict__ W2t,
                         unsigned short* __restrict__ W3t, unsigned short* __restrict__ W4t)
{
  int idx = blockIdx.x * 256 + threadIdx.x;
  if (idx < 128) {
    float s = 0.f;
    for (int j = 0; j < 128; j++) { float v = K[idx * 128 + j]; s += v * v; }
    S[idx] = s;
  }
  int i = idx;
  if (i < 16384) {                        // Kt[n][k] = K[k][n]; i over source K
    int k = i >> 7, n = i & 127;
    Kt[n * 128 + k] = f2bf(K[i]);
  } else if ((i -= 16384) < 25600) {      // W1t[n][k] = W1[k][n]; i over source W1 [128][200]
    int k = i / 200, n = i - k * 200;
    W1t[n * 128 + k] = f2bf(W1[i]);
  } else if ((i -= 25600) < 3072) {       // W1t zero rows n in [200,224)
    int n = 200 + (i >> 7), k = i & 127;
    W1t[n * 128 + k] = 0;
  } else if ((i -= 3072) < 51200) {       // W2t[n][k] = W2[k][n]; source W2 [200][256]
    int k = i >> 8, n = i & 255;
    W2t[n * 224 + k] = f2bf(W2[i]);
  } else if ((i -= 51200) < 6144) {       // W2t zero k in [200,224), n in [0,256)
    int n = i / 24, k = 200 + (i - n * 24);
    W2t[n * 224 + k] = 0;
  } else if ((i -= 6144) < 51200) {       // W3t[n][k] = W3[k][n]; source W3 [256][200]
    int k = i / 200, n = i - k * 200;
    W3t[n * 256 + k] = f2bf(W3[i]);
  } else if ((i -= 51200) < 6144) {       // W3t zero rows n in [200,224)
    int n = 200 + (i >> 8), k = i & 255;
    W3t[n * 256 + k] = 0;
  } else if ((i -= 6144) < 25600) {       // W4t[n][k] = W4[k][n]; source W4 [200][128]
    int k = i >> 7, n = i & 127;
    W4t[n * 224 + k] = f2bf(W4[i]);
  } else if ((i -= 25600) < 3072) {       // W4t zero k in [200,224), n in [0,128)
    int n = i / 24, k = 200 + (i - n * 24);
    W4t[n * 224 + k] = 0;
  }
}

// ---------------- generic MFMA layer, single shared activation buffer ----------------
// Reads act (K=KP), computes NT column-tiles, barrier, writes back into act.
template <int KP, int NT, int NREAL>
static __device__ __forceinline__ void gemm_layer(const unsigned short* __restrict__ wt,
                                                  const float* __restrict__ bias,
                                                  unsigned short* act,
                                                  int m, int qd, int wave)
{
  floatx4 acc[NT];
#pragma unroll
  for (int n = 0; n < NT; n++) acc[n] = {0.f, 0.f, 0.f, 0.f};
#pragma unroll
  for (int ks = 0; ks < KP / 32; ks++) {
    short8 a = *(const short8*)&act[(wave * 16 + m) * LSTR + ks * 32 + qd * 8];
#pragma unroll
    for (int n = 0; n < NT; n++) {
      short8 b = *(const short8*)&wt[(n * 16 + m) * KP + ks * 32 + qd * 8];
      acc[n] = __builtin_amdgcn_mfma_f32_16x16x32_bf16(a, b, acc[n], 0, 0, 0);
    }
  }
  __syncthreads();  // all waves done READING act; safe to overwrite
#pragma unroll
  for (int n = 0; n < NT; n++) {
    int col = n * 16 + m;
    float bv = (col < NREAL) ? bias[col] : 0.f;
#pragma unroll
    for (int i = 0; i < 4; i++) {
      float v = fmaxf(acc[n][i] + bv, 0.f);  // padded cols: 0+0 -> 0
      act[(wave * 16 + qd * 4 + i) * LSTR + col] = f2bf(v);
    }
  }
  __syncthreads();
}

// ---------------- fused main kernel ----------------
// Single activation buffer: LDS ~35.8 KB/block -> 4 blocks/CU (vs 2 with ping-pong).
// __launch_bounds__(256,4): cap VGPR at 128 so 4 waves/SIMD = 16 waves/CU.
__global__ __launch_bounds__(256, 4)
void dfm_main(const int* __restrict__ uidx, const int* __restrict__ iidx,
              const float* __restrict__ uemb, const float* __restrict__ iemb,
              const float* __restrict__ linw, const float* __restrict__ linb,
              const float* __restrict__ b1, const float* __restrict__ b2,
              const float* __restrict__ b3, const float* __restrict__ b4,
              const float* __restrict__ W5, const float* __restrict__ b5,
              const float* __restrict__ S, const unsigned short* __restrict__ Wc,
              const unsigned short* __restrict__ W2t, const unsigned short* __restrict__ W3t,
              const unsigned short* __restrict__ W4t,
              float* __restrict__ out)
{
  __shared__ unsigned short act[BM * LSTR];
  __shared__ float qrow[BM], linrow[BM], crossrow[BM], part[BM][4];

  const int t = threadIdx.x;
  const int lane = t & 63, wave = t >> 6;
  const int m = lane & 15, qd = lane >> 4;
  const int r = t >> 2, c = t & 3;

  // ---- gather + linear + q = sum(x^2 * rowsum(K^2)) ----
  {
    int g = blockIdx.x * BM + r;
    int u = uidx[g], it = iidx[g];
    const float* up = uemb + (long)u * EMBD + c * 16;
    const float* ip = iemb + (long)it * EMBD + c * 16;
    float qp = 0.f;
#pragma unroll
    for (int j = 0; j < 16; j += 4) {
      float4 f = *(const float4*)(up + j);
      int col = c * 16 + j;
      float4 sv = *(const float4*)(S + col);
      ushortx4 h = {f2bf(f.x), f2bf(f.y), f2bf(f.z), f2bf(f.w)};
      *(ushortx4*)&act[r * LSTR + col] = h;
      qp += f.x * f.x * sv.x + f.y * f.y * sv.y + f.z * f.z * sv.z + f.w * f.w * sv.w;
    }
#pragma unroll
    for (int j = 0; j < 16; j += 4) {
      float4 f = *(const float4*)(ip + j);
      int col = 64 + c * 16 + j;
      float4 sv = *(const float4*)(S + col);
      ushortx4 h = {f2bf(f.x), f2bf(f.y), f2bf(f.z), f2bf(f.w)};
      *(ushortx4*)&act[r * LSTR + col] = h;
      qp += f.x * f.x * sv.x + f.y * f.y * sv.y + f.z * f.z * sv.z + f.w * f.w * sv.w;
    }
    part[r][c] = qp;
    if (c == 0) linrow[r] = linw[u] + linw[HASH_BINS + it] + linb[0];
  }
  __syncthreads();
  if (c == 0) qrow[r] = part[r][0] + part[r][1] + part[r][2] + part[r][3];
  __syncthreads();

  // ---- fused cross (NT 0..7) + layer1 (NT 8..21), K=128 ----
  {
    floatx4 acc[22];
#pragma unroll
    for (int n = 0; n < 22; n++) acc[n] = {0.f, 0.f, 0.f, 0.f};
#pragma unroll
    for (int ks = 0; ks < 4; ks++) {
      short8 a = *(const short8*)&act[(wave * 16 + m) * LSTR + ks * 32 + qd * 8];
#pragma unroll
      for (int n = 0; n < 22; n++) {
        short8 b = *(const short8*)&Wc[(n * 16 + m) * 128 + ks * 32 + qd * 8];
        acc[n] = __builtin_amdgcn_mfma_f32_16x16x32_bf16(a, b, acc[n], 0, 0, 0);
      }
    }
    // cross: sum_j xk^2 per row, straight from accumulators
    float s0 = 0, s1 = 0, s2 = 0, s3 = 0;
#pragma unroll
    for (int n = 0; n < 8; n++) {
      s0 += acc[n][0] * acc[n][0];
      s1 += acc[n][1] * acc[n][1];
      s2 += acc[n][2] * acc[n][2];
      s3 += acc[n][3] * acc[n][3];
    }
#pragma unroll
    for (int mask = 1; mask < 16; mask <<= 1) {
      s0 += __shfl_xor(s0, mask, 64);
      s1 += __shfl_xor(s1, mask, 64);
      s2 += __shfl_xor(s2, mask, 64);
      s3 += __shfl_xor(s3, mask, 64);
    }
    if (m == 0) {
      int row = wave * 16 + qd * 4;
      const float inv = 0.5f / 128.f;
      crossrow[row + 0] = inv * (s0 - qrow[row + 0]);
      crossrow[row + 1] = inv * (s1 - qrow[row + 1]);
      crossrow[row + 2] = inv * (s2 - qrow[row + 2]);
      crossrow[row + 3] = inv * (s3 - qrow[row + 3]);
    }
    __syncthreads();  // all waves done reading act (and qrow)
    // layer1 epilogue: bias + relu -> act cols 0..223 (200..223 become 0)
#pragma unroll
    for (int n = 8; n < 22; n++) {
      int col = (n - 8) * 16 + m;
      float bv = (col < 200) ? b1[col] : 0.f;
#pragma unroll
      for (int i = 0; i < 4; i++) {
        float v = fmaxf(acc[n][i] + bv, 0.f);
        act[(wave * 16 + qd * 4 + i) * LSTR + col] = f2bf(v);
      }
    }
  }
  __syncthreads();

  gemm_layer<224, 16, 256>(W2t, b2, act, m, qd, wave);  // 224 -> 256
  gemm_layer<256, 14, 200>(W3t, b3, act, m, qd, wave);  // 256 -> 224(200)
  gemm_layer<224, 8, 128>(W4t, b4, act, m, qd, wave);   // 224 -> 128

  // ---- final dot with W5 (fp32) + sigmoid; vectorized ds_read_b128 ----
  {
    float d = 0.f;
    const unsigned short* ap = &act[r * LSTR + c * 32];
#pragma unroll
    for (int j = 0; j < 4; j++) {
      short8 h = *(const short8*)(ap + j * 8);
      float4 w0 = *(const float4*)(W5 + c * 32 + j * 8);
      float4 w1 = *(const float4*)(W5 + c * 32 + j * 8 + 4);
      d += bf2f((unsigned short)h[0]) * w0.x + bf2f((unsigned short)h[1]) * w0.y +
           bf2f((unsigned short)h[2]) * w0.z + bf2f((unsigned short)h[3]) * w0.w +
           bf2f((unsigned short)h[4]) * w1.x + bf2f((unsigned short)h[5]) * w1.y +
           bf2f((unsigned short)h[6]) * w1.z + bf2f((unsigned short)h[7]) * w1.w;
    }
    part[r][c] = d;
    __syncthreads();
    if (c == 0) {
      float logit = linrow[r] + crossrow[r] + part[r][0] + part[r][1] + part[r][2] + part[r][3] + b5[0];
      out[blockIdx.x * BM + r] = 1.f / (1.f + expf(-logit));
    }
  }
}

extern "C" void kernel_launch(void* const* d_in, const int* in_sizes, int n_in,
                              void* d_out, int out_size, void* d_ws, size_t ws_size,
                              hipStream_t stream)
{
  const int*   uidx = (const int*)d_in[0];
  const int*   iidx = (const int*)d_in[1];
  const float* uemb = (const float*)d_in[2];
  const float* iemb = (const float*)d_in[3];
  const float* linw = (const float*)d_in[4];
  const float* linb = (const float*)d_in[5];
  const float* K    = (const float*)d_in[6];
  const float* W1   = (const float*)d_in[7];
  const float* b1   = (const float*)d_in[8];
  const float* W2   = (const float*)d_in[9];
  const float* b2   = (const float*)d_in[10];
  const float* W3   = (const float*)d_in[11];
  const float* b3   = (const float*)d_in[12];
  const float* W4   = (const float*)d_in[13];
  const float* b4   = (const float*)d_in[14];
  const float* W5   = (const float*)d_in[15];
  const float* b5   = (const float*)d_in[16];

  char* w = (char*)d_ws;
  float* S = (float*)w;
  unsigned short* Kt  = (unsigned short*)(w + 512);
  unsigned short* W1t = (unsigned short*)(w + 33280);
  unsigned short* W2t = (unsigned short*)(w + 90624);
  unsigned short* W3t = (unsigned short*)(w + 205312);
  unsigned short* W4t = (unsigned short*)(w + 320000);
  float* out = (float*)d_out;

  dfm_prep<<<736, 256, 0, stream>>>(K, W1, W2, W3, W4, S, Kt, W1t, W2t, W3t, W4t);
  dfm_main<<<BATCH / BM, 256, 0, stream>>>(uidx, iidx, uemb, iemb, linw, linb,
                                           b1, b2, b3, b4, W5, b5,
                                           S, Kt, W2t, W3t, W4t, out);
}

// Round 3
// 760.853 us; speedup vs baseline: 1.0023x; 1.0023x over previous
//
#include <hip/hip_runtime.h>

#define HASH_BINS 100000
#define EMBD 64
#define BATCH 262144
#define BM 64
#define LSTR 264  // LDS activation row stride (bf16 elems); 264*2=528B breaks 32-bank alignment

typedef __attribute__((ext_vector_type(8))) short short8;
typedef __attribute__((ext_vector_type(4))) float floatx4;
typedef __attribute__((ext_vector_type(4))) unsigned short ushortx4;

static __device__ __forceinline__ unsigned short f2bf(float f) {
  unsigned u = __builtin_bit_cast(unsigned, f);
  u += 0x7fff + ((u >> 16) & 1);  // round-to-nearest-even
  return (unsigned short)(u >> 16);
}
static __device__ __forceinline__ float bf2f(unsigned short b) {
  return __builtin_bit_cast(float, ((unsigned)b) << 16);
}

// ---------------- prep: build bf16 transposed/padded weights in ws ----------------
// ws layout (bytes):
//   0      : S   fp32 [128]            (rowsum of cross_k^2)
//   512    : Kt  bf16 [128][128]       (cross_k transposed)   } contiguous => combined
//   33280  : W1t bf16 [224][128]       (W1 transposed, N-pad) } [352][128] matrix
//   90624  : W2t bf16 [256][224]       (K-pad 200->224)
//   205312 : W3t bf16 [224][256]       (N-pad 200->224)
//   320000 : W4t bf16 [128][224]       (K-pad 200->224)
// Copy segments iterate over the SOURCE layout so global reads are coalesced.
__global__ void dfm_prep(const float* __restrict__ K, const float* __restrict__ W1,
                         const float* __restrict__ W2, const float* __restrict__ W3,
                         const float* __restrict__ W4,
                         float* __restrict__ S, unsigned short* __restrict__ Kt,
                         unsigned short* __restrict__ W1t, unsigned short* __restrict__ W2t,
                         unsigned short* __restrict__ W3t, unsigned short* __restrict__ W4t)
{
  int idx = blockIdx.x * 256 + threadIdx.x;
  if (idx < 128) {
    float s = 0.f;
    for (int j = 0; j < 128; j++) { float v = K[idx * 128 + j]; s += v * v; }
    S[idx] = s;
  }
  int i = idx;
  if (i < 16384) {                        // Kt[n][k] = K[k][n]; i over source K
    int k = i >> 7, n = i & 127;
    Kt[n * 128 + k] = f2bf(K[i]);
  } else if ((i -= 16384) < 25600) {      // W1t[n][k] = W1[k][n]; i over source W1 [128][200]
    int k = i / 200, n = i - k * 200;
    W1t[n * 128 + k] = f2bf(W1[i]);
  } else if ((i -= 25600) < 3072) {       // W1t zero rows n in [200,224)
    int n = 200 + (i >> 7), k = i & 127;
    W1t[n * 128 + k] = 0;
  } else if ((i -= 3072) < 51200) {       // W2t[n][k] = W2[k][n]; source W2 [200][256]
    int k = i >> 8, n = i & 255;
    W2t[n * 224 + k] = f2bf(W2[i]);
  } else if ((i -= 51200) < 6144) {       // W2t zero k in [200,224), n in [0,256)
    int n = i / 24, k = 200 + (i - n * 24);
    W2t[n * 224 + k] = 0;
  } else if ((i -= 6144) < 51200) {       // W3t[n][k] = W3[k][n]; source W3 [256][200]
    int k = i / 200, n = i - k * 200;
    W3t[n * 256 + k] = f2bf(W3[i]);
  } else if ((i -= 51200) < 6144) {       // W3t zero rows n in [200,224)
    int n = 200 + (i >> 8), k = i & 255;
    W3t[n * 256 + k] = 0;
  } else if ((i -= 6144) < 25600) {       // W4t[n][k] = W4[k][n]; source W4 [200][128]
    int k = i >> 7, n = i & 127;
    W4t[n * 224 + k] = f2bf(W4[i]);
  } else if ((i -= 25600) < 3072) {       // W4t zero k in [200,224), n in [0,128)
    int n = i / 24, k = 200 + (i - n * 24);
    W4t[n * 224 + k] = 0;
  }
}

// ---------------- generic MFMA layer, single shared activation buffer ----------------
template <int KP, int NT, int NREAL>
static __device__ __forceinline__ void gemm_layer(const unsigned short* __restrict__ wt,
                                                  const float* __restrict__ bias,
                                                  unsigned short* act,
                                                  int m, int qd, int wave)
{
  floatx4 acc[NT];
#pragma unroll
  for (int n = 0; n < NT; n++) acc[n] = {0.f, 0.f, 0.f, 0.f};
  for (int ks = 0; ks < KP / 32; ks++) {
    short8 a = *(const short8*)&act[(wave * 16 + m) * LSTR + ks * 32 + qd * 8];
#pragma unroll
    for (int n = 0; n < NT; n++) {
      short8 b = *(const short8*)&wt[(n * 16 + m) * KP + ks * 32 + qd * 8];
      acc[n] = __builtin_amdgcn_mfma_f32_16x16x32_bf16(a, b, acc[n], 0, 0, 0);
    }
  }
  __syncthreads();  // all waves done READING act; safe to overwrite
#pragma unroll
  for (int n = 0; n < NT; n++) {
    int col = n * 16 + m;
    float bv = (col < NREAL) ? bias[col] : 0.f;
#pragma unroll
    for (int i = 0; i < 4; i++) {
      float v = fmaxf(acc[n][i] + bv, 0.f);  // padded cols: 0+0 -> 0
      act[(wave * 16 + qd * 4 + i) * LSTR + col] = f2bf(v);
    }
  }
  __syncthreads();
}

// ---------------- fused main kernel ----------------
// Single activation buffer: LDS ~35.8 KB/block -> 4 blocks/CU.
// amdgpu_waves_per_eu(4,4): VGPR budget exactly 512/4=128 (fits, round 1 proved it);
// avoids the (256,4) launch-bounds range that made the allocator chase 64 VGPR and spill.
__global__ __launch_bounds__(256)
__attribute__((amdgpu_waves_per_eu(4, 4)))
void dfm_main(const int* __restrict__ uidx, const int* __restrict__ iidx,
              const float* __restrict__ uemb, const float* __restrict__ iemb,
              const float* __restrict__ linw, const float* __restrict__ linb,
              const float* __restrict__ b1, const float* __restrict__ b2,
              const float* __restrict__ b3, const float* __restrict__ b4,
              const float* __restrict__ W5, const float* __restrict__ b5,
              const float* __restrict__ S, const unsigned short* __restrict__ Wc,
              const unsigned short* __restrict__ W2t, const unsigned short* __restrict__ W3t,
              const unsigned short* __restrict__ W4t,
              float* __restrict__ out)
{
  __shared__ unsigned short act[BM * LSTR];
  __shared__ float qrow[BM], linrow[BM], crossrow[BM], part[BM][4];

  const int t = threadIdx.x;
  const int lane = t & 63, wave = t >> 6;
  const int m = lane & 15, qd = lane >> 4;
  const int r = t >> 2, c = t & 3;

  // ---- gather + linear + q = sum(x^2 * rowsum(K^2)) ----
  {
    int g = blockIdx.x * BM + r;
    int u = uidx[g], it = iidx[g];
    const float* up = uemb + (long)u * EMBD + c * 16;
    const float* ip = iemb + (long)it * EMBD + c * 16;
    float qp = 0.f;
#pragma unroll
    for (int j = 0; j < 16; j += 4) {
      float4 f = *(const float4*)(up + j);
      int col = c * 16 + j;
      float4 sv = *(const float4*)(S + col);
      ushortx4 h = {f2bf(f.x), f2bf(f.y), f2bf(f.z), f2bf(f.w)};
      *(ushortx4*)&act[r * LSTR + col] = h;
      qp += f.x * f.x * sv.x + f.y * f.y * sv.y + f.z * f.z * sv.z + f.w * f.w * sv.w;
    }
#pragma unroll
    for (int j = 0; j < 16; j += 4) {
      float4 f = *(const float4*)(ip + j);
      int col = 64 + c * 16 + j;
      float4 sv = *(const float4*)(S + col);
      ushortx4 h = {f2bf(f.x), f2bf(f.y), f2bf(f.z), f2bf(f.w)};
      *(ushortx4*)&act[r * LSTR + col] = h;
      qp += f.x * f.x * sv.x + f.y * f.y * sv.y + f.z * f.z * sv.z + f.w * f.w * sv.w;
    }
    part[r][c] = qp;
    if (c == 0) linrow[r] = linw[u] + linw[HASH_BINS + it] + linb[0];
  }
  __syncthreads();
  if (c == 0) qrow[r] = part[r][0] + part[r][1] + part[r][2] + part[r][3];
  __syncthreads();

  // ---- fused cross (NT 0..7) + layer1 (NT 8..21), K=128 ----
  {
    floatx4 acc[22];
#pragma unroll
    for (int n = 0; n < 22; n++) acc[n] = {0.f, 0.f, 0.f, 0.f};
    for (int ks = 0; ks < 4; ks++) {
      short8 a = *(const short8*)&act[(wave * 16 + m) * LSTR + ks * 32 + qd * 8];
#pragma unroll
      for (int n = 0; n < 22; n++) {
        short8 b = *(const short8*)&Wc[(n * 16 + m) * 128 + ks * 32 + qd * 8];
        acc[n] = __builtin_amdgcn_mfma_f32_16x16x32_bf16(a, b, acc[n], 0, 0, 0);
      }
    }
    // cross: sum_j xk^2 per row, straight from accumulators
    float s0 = 0, s1 = 0, s2 = 0, s3 = 0;
#pragma unroll
    for (int n = 0; n < 8; n++) {
      s0 += acc[n][0] * acc[n][0];
      s1 += acc[n][1] * acc[n][1];
      s2 += acc[n][2] * acc[n][2];
      s3 += acc[n][3] * acc[n][3];
    }
#pragma unroll
    for (int mask = 1; mask < 16; mask <<= 1) {
      s0 += __shfl_xor(s0, mask, 64);
      s1 += __shfl_xor(s1, mask, 64);
      s2 += __shfl_xor(s2, mask, 64);
      s3 += __shfl_xor(s3, mask, 64);
    }
    if (m == 0) {
      int row = wave * 16 + qd * 4;
      const float inv = 0.5f / 128.f;
      crossrow[row + 0] = inv * (s0 - qrow[row + 0]);
      crossrow[row + 1] = inv * (s1 - qrow[row + 1]);
      crossrow[row + 2] = inv * (s2 - qrow[row + 2]);
      crossrow[row + 3] = inv * (s3 - qrow[row + 3]);
    }
    __syncthreads();  // all waves done reading act (and qrow)
    // layer1 epilogue: bias + relu -> act cols 0..223 (200..223 become 0)
#pragma unroll
    for (int n = 8; n < 22; n++) {
      int col = (n - 8) * 16 + m;
      float bv = (col < 200) ? b1[col] : 0.f;
#pragma unroll
      for (int i = 0; i < 4; i++) {
        float v = fmaxf(acc[n][i] + bv, 0.f);
        act[(wave * 16 + qd * 4 + i) * LSTR + col] = f2bf(v);
      }
    }
  }
  __syncthreads();

  gemm_layer<224, 16, 256>(W2t, b2, act, m, qd, wave);  // 224 -> 256
  gemm_layer<256, 14, 200>(W3t, b3, act, m, qd, wave);  // 256 -> 224(200)
  gemm_layer<224, 8, 128>(W4t, b4, act, m, qd, wave);   // 224 -> 128

  // ---- final dot with W5 (fp32) + sigmoid; vectorized ds_read_b128 ----
  {
    float d = 0.f;
    const unsigned short* ap = &act[r * LSTR + c * 32];
#pragma unroll
    for (int j = 0; j < 4; j++) {
      short8 h = *(const short8*)(ap + j * 8);
      float4 w0 = *(const float4*)(W5 + c * 32 + j * 8);
      float4 w1 = *(const float4*)(W5 + c * 32 + j * 8 + 4);
      d += bf2f((unsigned short)h[0]) * w0.x + bf2f((unsigned short)h[1]) * w0.y +
           bf2f((unsigned short)h[2]) * w0.z + bf2f((unsigned short)h[3]) * w0.w +
           bf2f((unsigned short)h[4]) * w1.x + bf2f((unsigned short)h[5]) * w1.y +
           bf2f((unsigned short)h[6]) * w1.z + bf2f((unsigned short)h[7]) * w1.w;
    }
    part[r][c] = d;
    __syncthreads();
    if (c == 0) {
      float logit = linrow[r] + crossrow[r] + part[r][0] + part[r][1] + part[r][2] + part[r][3] + b5[0];
      out[blockIdx.x * BM + r] = 1.f / (1.f + expf(-logit));
    }
  }
}

extern "C" void kernel_launch(void* const* d_in, const int* in_sizes, int n_in,
                              void* d_out, int out_size, void* d_ws, size_t ws_size,
                              hipStream_t stream)
{
  const int*   uidx = (const int*)d_in[0];
  const int*   iidx = (const int*)d_in[1];
  const float* uemb = (const float*)d_in[2];
  const float* iemb = (const float*)d_in[3];
  const float* linw = (const float*)d_in[4];
  const float* linb = (const float*)d_in[5];
  const float* K    = (const float*)d_in[6];
  const float* W1   = (const float*)d_in[7];
  const float* b1   = (const float*)d_in[8];
  const float* W2   = (const float*)d_in[9];
  const float* b2   = (const float*)d_in[10];
  const float* W3   = (const float*)d_in[11];
  const float* b3   = (const float*)d_in[12];
  const float* W4   = (const float*)d_in[13];
  const float* b4   = (const float*)d_in[14];
  const float* W5   = (const float*)d_in[15];
  const float* b5   = (const float*)d_in[16];

  char* w = (char*)d_ws;
  float* S = (float*)w;
  unsigned short* Kt  = (unsigned short*)(w + 512);
  unsigned short* W1t = (unsigned short*)(w + 33280);
  unsigned short* W2t = (unsigned short*)(w + 90624);
  unsigned short* W3t = (unsigned short*)(w + 205312);
  unsigned short* W4t = (unsigned short*)(w + 320000);
  float* out = (float*)d_out;

  dfm_prep<<<736, 256, 0, stream>>>(K, W1, W2, W3, W4, S, Kt, W1t, W2t, W3t, W4t);
  dfm_main<<<BATCH / BM, 256, 0, stream>>>(uidx, iidx, uemb, iemb, linw, linb,
                                           b1, b2, b3, b4, W5, b5,
                                           S, Kt, W2t, W3t, W4t, out);
}

// Round 4
// 736.027 us; speedup vs baseline: 1.0361x; 1.0337x over previous
//
#include <hip/hip_runtime.h>

#define HASH_BINS 100000
#define EMBD 64
#define BATCH 262144
#define BM 64
#define LSTR 264  // LDS activation row stride (bf16 elems); 264*2=528B breaks 32-bank alignment

typedef __attribute__((ext_vector_type(8))) short short8;
typedef __attribute__((ext_vector_type(4))) float floatx4;
typedef __attribute__((ext_vector_type(4))) unsigned short ushortx4;

static __device__ __forceinline__ unsigned short f2bf(float f) {
  unsigned u = __builtin_bit_cast(unsigned, f);
  u += 0x7fff + ((u >> 16) & 1);  // round-to-nearest-even
  return (unsigned short)(u >> 16);
}
static __device__ __forceinline__ float bf2f(unsigned short b) {
  return __builtin_bit_cast(float, ((unsigned)b) << 16);
}

// ---------------- prep: build bf16 transposed/padded weights in ws ----------------
// ws layout (bytes):
//   0      : S   fp32 [128]            (rowsum of cross_k^2)
//   512    : Kt  bf16 [128][128]       (cross_k transposed)   } contiguous => combined
//   33280  : W1t bf16 [224][128]       (W1 transposed, N-pad) } [352][128] matrix
//   90624  : W2t bf16 [256][224]       (K-pad 200->224)
//   205312 : W3t bf16 [224][256]       (N-pad 200->224)
//   320000 : W4t bf16 [128][224]       (K-pad 200->224)
// Copy segments iterate over the SOURCE layout so global reads are coalesced.
__global__ void dfm_prep(const float* __restrict__ K, const float* __restrict__ W1,
                         const float* __restrict__ W2, const float* __restrict__ W3,
                         const float* __restrict__ W4,
                         float* __restrict__ S, unsigned short* __restrict__ Kt,
                         unsigned short* __restrict__ W1t, unsigned short* __restrict__ W2t,
                         unsigned short* __restrict__ W3t, unsigned short* __restrict__ W4t)
{
  int idx = blockIdx.x * 256 + threadIdx.x;
  if (idx < 128) {
    float s = 0.f;
    for (int j = 0; j < 128; j++) { float v = K[idx * 128 + j]; s += v * v; }
    S[idx] = s;
  }
  int i = idx;
  if (i < 16384) {                        // Kt[n][k] = K[k][n]; i over source K
    int k = i >> 7, n = i & 127;
    Kt[n * 128 + k] = f2bf(K[i]);
  } else if ((i -= 16384) < 25600) {      // W1t[n][k] = W1[k][n]; i over source W1 [128][200]
    int k = i / 200, n = i - k * 200;
    W1t[n * 128 + k] = f2bf(W1[i]);
  } else if ((i -= 25600) < 3072) {       // W1t zero rows n in [200,224)
    int n = 200 + (i >> 7), k = i & 127;
    W1t[n * 128 + k] = 0;
  } else if ((i -= 3072) < 51200) {       // W2t[n][k] = W2[k][n]; source W2 [200][256]
    int k = i >> 8, n = i & 255;
    W2t[n * 224 + k] = f2bf(W2[i]);
  } else if ((i -= 51200) < 6144) {       // W2t zero k in [200,224), n in [0,256)
    int n = i / 24, k = 200 + (i - n * 24);
    W2t[n * 224 + k] = 0;
  } else if ((i -= 6144) < 51200) {       // W3t[n][k] = W3[k][n]; source W3 [256][200]
    int k = i / 200, n = i - k * 200;
    W3t[n * 256 + k] = f2bf(W3[i]);
  } else if ((i -= 51200) < 6144) {       // W3t zero rows n in [200,224)
    int n = 200 + (i >> 8), k = i & 255;
    W3t[n * 256 + k] = 0;
  } else if ((i -= 6144) < 25600) {       // W4t[n][k] = W4[k][n]; source W4 [200][128]
    int k = i >> 7, n = i & 127;
    W4t[n * 224 + k] = f2bf(W4[i]);
  } else if ((i -= 25600) < 3072) {       // W4t zero k in [200,224), n in [0,128)
    int n = i / 24, k = 200 + (i - n * 24);
    W4t[n * 224 + k] = 0;
  }
}

// ---------------- generic MFMA layer, single shared activation buffer ----------------
template <int KP, int NT, int NREAL>
static __device__ __forceinline__ void gemm_layer(const unsigned short* __restrict__ wt,
                                                  const float* __restrict__ bias,
                                                  unsigned short* act,
                                                  int m, int qd, int wave)
{
  floatx4 acc[NT];
#pragma unroll
  for (int n = 0; n < NT; n++) acc[n] = {0.f, 0.f, 0.f, 0.f};
  for (int ks = 0; ks < KP / 32; ks++) {
    short8 a = *(const short8*)&act[(wave * 16 + m) * LSTR + ks * 32 + qd * 8];
#pragma unroll
    for (int n = 0; n < NT; n++) {
      short8 b = *(const short8*)&wt[(n * 16 + m) * KP + ks * 32 + qd * 8];
      acc[n] = __builtin_amdgcn_mfma_f32_16x16x32_bf16(a, b, acc[n], 0, 0, 0);
    }
  }
  __syncthreads();  // all waves done READING act; safe to overwrite
#pragma unroll
  for (int n = 0; n < NT; n++) {
    int col = n * 16 + m;
    float bv = (col < NREAL) ? bias[col] : 0.f;
#pragma unroll
    for (int i = 0; i < 4; i++) {
      float v = fmaxf(acc[n][i] + bv, 0.f);  // padded cols: 0+0 -> 0
      act[(wave * 16 + qd * 4 + i) * LSTR + col] = f2bf(v);
    }
  }
  __syncthreads();
}

// ---------------- fused main kernel ----------------
// Single activation buffer: LDS ~35.8 KB/block -> 4 blocks/CU by LDS.
// __launch_bounds__(256, 2): empirically VGPR budget 128 on this toolchain
// (R1: 128 VGPR, zero spill). (256,4)/waves_per_eu(4,4) both forced 64 VGPR
// -> 574 MB scratch spill (R2/R3). Occupancy at dispatch: min(LDS 4, VGPR 4) blocks/CU.
__global__ __launch_bounds__(256, 2)
void dfm_main(const int* __restrict__ uidx, const int* __restrict__ iidx,
              const float* __restrict__ uemb, const float* __restrict__ iemb,
              const float* __restrict__ linw, const float* __restrict__ linb,
              const float* __restrict__ b1, const float* __restrict__ b2,
              const float* __restrict__ b3, const float* __restrict__ b4,
              const float* __restrict__ W5, const float* __restrict__ b5,
              const float* __restrict__ S, const unsigned short* __restrict__ Wc,
              const unsigned short* __restrict__ W2t, const unsigned short* __restrict__ W3t,
              const unsigned short* __restrict__ W4t,
              float* __restrict__ out)
{
  __shared__ unsigned short act[BM * LSTR];
  __shared__ float qrow[BM], linrow[BM], crossrow[BM], part[BM][4];

  const int t = threadIdx.x;
  const int lane = t & 63, wave = t >> 6;
  const int m = lane & 15, qd = lane >> 4;
  const int r = t >> 2, c = t & 3;

  // ---- gather + linear + q = sum(x^2 * rowsum(K^2)) ----
  {
    int g = blockIdx.x * BM + r;
    int u = uidx[g], it = iidx[g];
    const float* up = uemb + (long)u * EMBD + c * 16;
    const float* ip = iemb + (long)it * EMBD + c * 16;
    float qp = 0.f;
#pragma unroll
    for (int j = 0; j < 16; j += 4) {
      float4 f = *(const float4*)(up + j);
      int col = c * 16 + j;
      float4 sv = *(const float4*)(S + col);
      ushortx4 h = {f2bf(f.x), f2bf(f.y), f2bf(f.z), f2bf(f.w)};
      *(ushortx4*)&act[r * LSTR + col] = h;
      qp += f.x * f.x * sv.x + f.y * f.y * sv.y + f.z * f.z * sv.z + f.w * f.w * sv.w;
    }
#pragma unroll
    for (int j = 0; j < 16; j += 4) {
      float4 f = *(const float4*)(ip + j);
      int col = 64 + c * 16 + j;
      float4 sv = *(const float4*)(S + col);
      ushortx4 h = {f2bf(f.x), f2bf(f.y), f2bf(f.z), f2bf(f.w)};
      *(ushortx4*)&act[r * LSTR + col] = h;
      qp += f.x * f.x * sv.x + f.y * f.y * sv.y + f.z * f.z * sv.z + f.w * f.w * sv.w;
    }
    part[r][c] = qp;
    if (c == 0) linrow[r] = linw[u] + linw[HASH_BINS + it] + linb[0];
  }
  __syncthreads();
  if (c == 0) qrow[r] = part[r][0] + part[r][1] + part[r][2] + part[r][3];
  __syncthreads();

  // ---- fused cross (NT 0..7) + layer1 (NT 8..21), K=128 ----
  {
    floatx4 acc[22];
#pragma unroll
    for (int n = 0; n < 22; n++) acc[n] = {0.f, 0.f, 0.f, 0.f};
    for (int ks = 0; ks < 4; ks++) {
      short8 a = *(const short8*)&act[(wave * 16 + m) * LSTR + ks * 32 + qd * 8];
#pragma unroll
      for (int n = 0; n < 22; n++) {
        short8 b = *(const short8*)&Wc[(n * 16 + m) * 128 + ks * 32 + qd * 8];
        acc[n] = __builtin_amdgcn_mfma_f32_16x16x32_bf16(a, b, acc[n], 0, 0, 0);
      }
    }
    // cross: sum_j xk^2 per row, straight from accumulators
    float s0 = 0, s1 = 0, s2 = 0, s3 = 0;
#pragma unroll
    for (int n = 0; n < 8; n++) {
      s0 += acc[n][0] * acc[n][0];
      s1 += acc[n][1] * acc[n][1];
      s2 += acc[n][2] * acc[n][2];
      s3 += acc[n][3] * acc[n][3];
    }
#pragma unroll
    for (int mask = 1; mask < 16; mask <<= 1) {
      s0 += __shfl_xor(s0, mask, 64);
      s1 += __shfl_xor(s1, mask, 64);
      s2 += __shfl_xor(s2, mask, 64);
      s3 += __shfl_xor(s3, mask, 64);
    }
    if (m == 0) {
      int row = wave * 16 + qd * 4;
      const float inv = 0.5f / 128.f;
      crossrow[row + 0] = inv * (s0 - qrow[row + 0]);
      crossrow[row + 1] = inv * (s1 - qrow[row + 1]);
      crossrow[row + 2] = inv * (s2 - qrow[row + 2]);
      crossrow[row + 3] = inv * (s3 - qrow[row + 3]);
    }
    __syncthreads();  // all waves done reading act (and qrow)
    // layer1 epilogue: bias + relu -> act cols 0..223 (200..223 become 0)
#pragma unroll
    for (int n = 8; n < 22; n++) {
      int col = (n - 8) * 16 + m;
      float bv = (col < 200) ? b1[col] : 0.f;
#pragma unroll
      for (int i = 0; i < 4; i++) {
        float v = fmaxf(acc[n][i] + bv, 0.f);
        act[(wave * 16 + qd * 4 + i) * LSTR + col] = f2bf(v);
      }
    }
  }
  __syncthreads();

  gemm_layer<224, 16, 256>(W2t, b2, act, m, qd, wave);  // 224 -> 256
  gemm_layer<256, 14, 200>(W3t, b3, act, m, qd, wave);  // 256 -> 224(200)
  gemm_layer<224, 8, 128>(W4t, b4, act, m, qd, wave);   // 224 -> 128

  // ---- final dot with W5 (fp32) + sigmoid; vectorized ds_read_b128 ----
  {
    float d = 0.f;
    const unsigned short* ap = &act[r * LSTR + c * 32];
#pragma unroll
    for (int j = 0; j < 4; j++) {
      short8 h = *(const short8*)(ap + j * 8);
      float4 w0 = *(const float4*)(W5 + c * 32 + j * 8);
      float4 w1 = *(const float4*)(W5 + c * 32 + j * 8 + 4);
      d += bf2f((unsigned short)h[0]) * w0.x + bf2f((unsigned short)h[1]) * w0.y +
           bf2f((unsigned short)h[2]) * w0.z + bf2f((unsigned short)h[3]) * w0.w +
           bf2f((unsigned short)h[4]) * w1.x + bf2f((unsigned short)h[5]) * w1.y +
           bf2f((unsigned short)h[6]) * w1.z + bf2f((unsigned short)h[7]) * w1.w;
    }
    part[r][c] = d;
    __syncthreads();
    if (c == 0) {
      float logit = linrow[r] + crossrow[r] + part[r][0] + part[r][1] + part[r][2] + part[r][3] + b5[0];
      out[blockIdx.x * BM + r] = 1.f / (1.f + expf(-logit));
    }
  }
}

extern "C" void kernel_launch(void* const* d_in, const int* in_sizes, int n_in,
                              void* d_out, int out_size, void* d_ws, size_t ws_size,
                              hipStream_t stream)
{
  const int*   uidx = (const int*)d_in[0];
  const int*   iidx = (const int*)d_in[1];
  const float* uemb = (const float*)d_in[2];
  const float* iemb = (const float*)d_in[3];
  const float* linw = (const float*)d_in[4];
  const float* linb = (const float*)d_in[5];
  const float* K    = (const float*)d_in[6];
  const float* W1   = (const float*)d_in[7];
  const float* b1   = (const float*)d_in[8];
  const float* W2   = (const float*)d_in[9];
  const float* b2   = (const float*)d_in[10];
  const float* W3   = (const float*)d_in[11];
  const float* b3   = (const float*)d_in[12];
  const float* W4   = (const float*)d_in[13];
  const float* b4   = (const float*)d_in[14];
  const float* W5   = (const float*)d_in[15];
  const float* b5   = (const float*)d_in[16];

  char* w = (char*)d_ws;
  float* S = (float*)w;
  unsigned short* Kt  = (unsigned short*)(w + 512);
  unsigned short* W1t = (unsigned short*)(w + 33280);
  unsigned short* W2t = (unsigned short*)(w + 90624);
  unsigned short* W3t = (unsigned short*)(w + 205312);
  unsigned short* W4t = (unsigned short*)(w + 320000);
  float* out = (float*)d_out;

  dfm_prep<<<736, 256, 0, stream>>>(K, W1, W2, W3, W4, S, Kt, W1t, W2t, W3t, W4t);
  dfm_main<<<BATCH / BM, 256, 0, stream>>>(uidx, iidx, uemb, iemb, linw, linb,
                                           b1, b2, b3, b4, W5, b5,
                                           S, Kt, W2t, W3t, W4t, out);
}

// Round 5
// 326.641 us; speedup vs baseline: 2.3348x; 2.2533x over previous
//
#include <hip/hip_runtime.h>

#define HASH_BINS 100000
#define EMBD 64
#define BATCH 262144
#define BM 64
#define SA 264  // act buffer A stride (bf16): 528B rows, 16B-aligned, 2-way bank alias (free)
#define SB 232  // act buffer B stride (bf16): 464B rows, 16B-aligned, 2-way bank alias (free)

typedef __attribute__((ext_vector_type(8))) short short8;
typedef __attribute__((ext_vector_type(4))) float floatx4;
typedef __attribute__((ext_vector_type(4))) unsigned short ushortx4;

static __device__ __forceinline__ unsigned short f2bf(float f) {
  unsigned u = __builtin_bit_cast(unsigned, f);
  u += 0x7fff + ((u >> 16) & 1);  // round-to-nearest-even
  return (unsigned short)(u >> 16);
}
static __device__ __forceinline__ float bf2f(unsigned short b) {
  return __builtin_bit_cast(float, ((unsigned)b) << 16);
}

// ---------------- prep: build bf16 transposed/padded weights in ws ----------------
// ws layout (bytes):
//   0      : S   fp32 [128]            (rowsum of cross_k^2)
//   512    : Kt  bf16 [128][128]       (cross_k transposed)   } contiguous => combined
//   33280  : W1t bf16 [224][128]       (W1 transposed, N-pad) } [352][128] matrix
//   90624  : W2t bf16 [256][224]       (K-pad 200->224)
//   205312 : W3t bf16 [224][256]       (N-pad 200->224)
//   320000 : W4t bf16 [128][224]       (K-pad 200->224)
__global__ void dfm_prep(const float* __restrict__ K, const float* __restrict__ W1,
                         const float* __restrict__ W2, const float* __restrict__ W3,
                         const float* __restrict__ W4,
                         float* __restrict__ S, unsigned short* __restrict__ Kt,
                         unsigned short* __restrict__ W1t, unsigned short* __restrict__ W2t,
                         unsigned short* __restrict__ W3t, unsigned short* __restrict__ W4t)
{
  int idx = blockIdx.x * 256 + threadIdx.x;
  if (idx < 128) {
    float s = 0.f;
    for (int j = 0; j < 128; j++) { float v = K[idx * 128 + j]; s += v * v; }
    S[idx] = s;
  }
  int i = idx;
  if (i < 16384) {                        // Kt[n][k] = K[k][n]; i over source K
    int k = i >> 7, n = i & 127;
    Kt[n * 128 + k] = f2bf(K[i]);
  } else if ((i -= 16384) < 25600) {      // W1t[n][k] = W1[k][n]; i over source W1 [128][200]
    int k = i / 200, n = i - k * 200;
    W1t[n * 128 + k] = f2bf(W1[i]);
  } else if ((i -= 25600) < 3072) {       // W1t zero rows n in [200,224)
    int n = 200 + (i >> 7), k = i & 127;
    W1t[n * 128 + k] = 0;
  } else if ((i -= 3072) < 51200) {       // W2t[n][k] = W2[k][n]; source W2 [200][256]
    int k = i >> 8, n = i & 255;
    W2t[n * 224 + k] = f2bf(W2[i]);
  } else if ((i -= 51200) < 6144) {       // W2t zero k in [200,224), n in [0,256)
    int n = i / 24, k = 200 + (i - n * 24);
    W2t[n * 224 + k] = 0;
  } else if ((i -= 6144) < 51200) {       // W3t[n][k] = W3[k][n]; source W3 [256][200]
    int k = i / 200, n = i - k * 200;
    W3t[n * 256 + k] = f2bf(W3[i]);
  } else if ((i -= 51200) < 6144) {       // W3t zero rows n in [200,224)
    int n = 200 + (i >> 8), k = i & 255;
    W3t[n * 256 + k] = 0;
  } else if ((i -= 6144) < 25600) {       // W4t[n][k] = W4[k][n]; source W4 [200][128]
    int k = i >> 7, n = i & 127;
    W4t[n * 224 + k] = f2bf(W4[i]);
  } else if ((i -= 25600) < 3072) {       // W4t zero k in [200,224), n in [0,128)
    int n = i / 24, k = 200 + (i - n * 24);
    W4t[n * 224 + k] = 0;
  }
}

// ---- MFMA pass: CH n-tiles x 4 row-tiles (all 64 rows), K=KP ----
// Each weight fragment is read by exactly ONE wave per block (N-partition).
template <int KP, int CH>
static __device__ __forceinline__ void mfma_pass(const unsigned short* __restrict__ wt,
                                                 int rowOff, const unsigned short* actIn,
                                                 int sin, int m, int qd, floatx4* acc)
{
#pragma unroll
  for (int i = 0; i < CH * 4; i++) acc[i] = {0.f, 0.f, 0.f, 0.f};
#pragma unroll
  for (int ks = 0; ks < KP / 32; ks++) {
    short8 a[4];
#pragma unroll
    for (int rt = 0; rt < 4; rt++)
      a[rt] = *(const short8*)&actIn[(rt * 16 + m) * sin + ks * 32 + qd * 8];
#pragma unroll
    for (int n = 0; n < CH; n++) {
      short8 b = *(const short8*)&wt[(rowOff + n * 16 + m) * KP + ks * 32 + qd * 8];
#pragma unroll
      for (int rt = 0; rt < 4; rt++)
        acc[n * 4 + rt] = __builtin_amdgcn_mfma_f32_16x16x32_bf16(a[rt], b, acc[n * 4 + rt], 0, 0, 0);
    }
  }
}

template <int CH>
static __device__ __forceinline__ void epilogue_relu(const float* __restrict__ bias,
                                                     int colBase, int nreal,
                                                     unsigned short* actOut, int sout,
                                                     int m, int qd, const floatx4* acc)
{
#pragma unroll
  for (int n = 0; n < CH; n++) {
    int col = colBase + n * 16 + m;
    float bv = (col < nreal) ? bias[col] : 0.f;
#pragma unroll
    for (int rt = 0; rt < 4; rt++)
#pragma unroll
      for (int i = 0; i < 4; i++) {
        float v = fmaxf(acc[n * 4 + rt][i] + bv, 0.f);  // padded cols: 0+0 -> 0
        actOut[(rt * 16 + qd * 4 + i) * sout + col] = f2bf(v);
      }
  }
}

// ---------------- fused main kernel ----------------
// Partition: each wave computes ALL 64 rows x 1/4 of the output tiles.
// Ping-pong act buffers (A: emb/W2out/W4out, B: L1out/W3out) -> 1 barrier per layer.
__global__ __launch_bounds__(256, 2)
void dfm_main(const int* __restrict__ uidx, const int* __restrict__ iidx,
              const float* __restrict__ uemb, const float* __restrict__ iemb,
              const float* __restrict__ linw, const float* __restrict__ linb,
              const float* __restrict__ b1, const float* __restrict__ b2,
              const float* __restrict__ b3, const float* __restrict__ b4,
              const float* __restrict__ W5, const float* __restrict__ b5,
              const float* __restrict__ S, const unsigned short* __restrict__ Wc,
              const unsigned short* __restrict__ W2t, const unsigned short* __restrict__ W3t,
              const unsigned short* __restrict__ W4t,
              float* __restrict__ out)
{
  __shared__ unsigned short actA[BM * SA];
  __shared__ unsigned short actB[BM * SB];
  __shared__ float crosspart[4][BM];
  __shared__ float part[BM][4];
  __shared__ float linrow[BM];

  const int t = threadIdx.x;
  const int lane = t & 63, wave = t >> 6;
  const int m = lane & 15, qd = lane >> 4;
  const int r = t >> 2, c = t & 3;

  // ---- gather + linear + q-partials (q = sum x^2 * rowsum(K^2)) ----
  {
    int g = blockIdx.x * BM + r;
    int u = uidx[g], it = iidx[g];
    const float* up = uemb + (long)u * EMBD + c * 16;
    const float* ip = iemb + (long)it * EMBD + c * 16;
    float qp = 0.f;
#pragma unroll
    for (int j = 0; j < 16; j += 4) {
      float4 f = *(const float4*)(up + j);
      int col = c * 16 + j;
      float4 sv = *(const float4*)(S + col);
      ushortx4 h = {f2bf(f.x), f2bf(f.y), f2bf(f.z), f2bf(f.w)};
      *(ushortx4*)&actA[r * SA + col] = h;
      qp += f.x * f.x * sv.x + f.y * f.y * sv.y + f.z * f.z * sv.z + f.w * f.w * sv.w;
    }
#pragma unroll
    for (int j = 0; j < 16; j += 4) {
      float4 f = *(const float4*)(ip + j);
      int col = 64 + c * 16 + j;
      float4 sv = *(const float4*)(S + col);
      ushortx4 h = {f2bf(f.x), f2bf(f.y), f2bf(f.z), f2bf(f.w)};
      *(ushortx4*)&actA[r * SA + col] = h;
      qp += f.x * f.x * sv.x + f.y * f.y * sv.y + f.z * f.z * sv.z + f.w * f.w * sv.w;
    }
    part[r][c] = qp;
    if (c == 0) linrow[r] = linw[u] + linw[HASH_BINS + it] + linb[0];
  }
  __syncthreads();  // B1: emb in actA

  // ---- fused layer (K=128, reads actA): cross tiles {2w,2w+1} + L1 share -> actB ----
  {
    floatx4 acc[8];
    mfma_pass<128, 2>(Wc, (2 * wave) * 16, actA, SA, m, qd, acc);
    // cross: per-row sum of xk^2 over this wave's 2 tiles
    float s[4][4];
#pragma unroll
    for (int rt = 0; rt < 4; rt++)
#pragma unroll
      for (int i = 0; i < 4; i++)
        s[rt][i] = acc[rt][i] * acc[rt][i] + acc[4 + rt][i] * acc[4 + rt][i];
#pragma unroll
    for (int mask = 1; mask < 16; mask <<= 1)
#pragma unroll
      for (int rt = 0; rt < 4; rt++)
#pragma unroll
        for (int i = 0; i < 4; i++)
          s[rt][i] += __shfl_xor(s[rt][i], mask, 64);
    if (m == 0)
#pragma unroll
      for (int rt = 0; rt < 4; rt++)
#pragma unroll
        for (int i = 0; i < 4; i++)
          crosspart[wave][rt * 16 + qd * 4 + i] = s[rt][i];
  }
  {
    // L1 tiles (14 total): shares {0-3, 4-7, 8-10, 11-13}
    int s0 = (wave < 3) ? wave * 4 : 11;
    if (wave < 2) {
      floatx4 acc[16];
      mfma_pass<128, 4>(Wc, 128 + s0 * 16, actA, SA, m, qd, acc);
      epilogue_relu<4>(b1, s0 * 16, 200, actB, SB, m, qd, acc);
    } else {
      floatx4 acc[12];
      mfma_pass<128, 3>(Wc, 128 + s0 * 16, actA, SA, m, qd, acc);
      epilogue_relu<3>(b1, s0 * 16, 200, actB, SB, m, qd, acc);
    }
  }
  __syncthreads();  // B2: L1 out (224 cols, zero-padded) in actB

  // ---- W2: K=224, actB -> actA, 16 tiles, share 4 each ----
  {
    floatx4 acc[16];
    mfma_pass<224, 4>(W2t, wave * 4 * 16, actB, SB, m, qd, acc);
    epilogue_relu<4>(b2, wave * 4 * 16, 256, actA, SA, m, qd, acc);
  }
  __syncthreads();  // B3: W2 out (256) in actA

  // ---- W3: K=256, actA -> actB, 14 tiles, shares {4,4,3,3} ----
  {
    int s0 = (wave < 3) ? wave * 4 : 11;
    if (wave < 2) {
      floatx4 acc[16];
      mfma_pass<256, 4>(W3t, s0 * 16, actA, SA, m, qd, acc);
      epilogue_relu<4>(b3, s0 * 16, 200, actB, SB, m, qd, acc);
    } else {
      floatx4 acc[12];
      mfma_pass<256, 3>(W3t, s0 * 16, actA, SA, m, qd, acc);
      epilogue_relu<3>(b3, s0 * 16, 200, actB, SB, m, qd, acc);
    }
  }
  __syncthreads();  // B4: W3 out (224, zero-padded) in actB

  // ---- W4: K=224, actB -> actA, 8 tiles, share 2 each ----
  {
    floatx4 acc[8];
    mfma_pass<224, 2>(W4t, wave * 2 * 16, actB, SB, m, qd, acc);
    epilogue_relu<2>(b4, wave * 2 * 16, 128, actA, SA, m, qd, acc);
  }
  __syncthreads();  // B5: W4 out (128) in actA

  // ---- final: W5 dot + cross combine + sigmoid ----
  {
    float qp = part[r][c];  // q-partial from gather phase
    float d = 0.f;
    const unsigned short* ap = &actA[r * SA + c * 32];
#pragma unroll
    for (int j = 0; j < 4; j++) {
      short8 h = *(const short8*)(ap + j * 8);
      float4 w0 = *(const float4*)(W5 + c * 32 + j * 8);
      float4 w1 = *(const float4*)(W5 + c * 32 + j * 8 + 4);
      d += bf2f((unsigned short)h[0]) * w0.x + bf2f((unsigned short)h[1]) * w0.y +
           bf2f((unsigned short)h[2]) * w0.z + bf2f((unsigned short)h[3]) * w0.w +
           bf2f((unsigned short)h[4]) * w1.x + bf2f((unsigned short)h[5]) * w1.y +
           bf2f((unsigned short)h[6]) * w1.z + bf2f((unsigned short)h[7]) * w1.w;
    }
    const float inv = 0.5f / 128.f;
    part[r][c] = d - inv * qp;  // dnn partial minus q share of cross
    __syncthreads();
    if (c == 0) {
      float xk2 = crosspart[0][r] + crosspart[1][r] + crosspart[2][r] + crosspart[3][r];
      float logit = linrow[r] + inv * xk2 +
                    part[r][0] + part[r][1] + part[r][2] + part[r][3] + b5[0];
      out[blockIdx.x * BM + r] = 1.f / (1.f + expf(-logit));
    }
  }
}

extern "C" void kernel_launch(void* const* d_in, const int* in_sizes, int n_in,
                              void* d_out, int out_size, void* d_ws, size_t ws_size,
                              hipStream_t stream)
{
  const int*   uidx = (const int*)d_in[0];
  const int*   iidx = (const int*)d_in[1];
  const float* uemb = (const float*)d_in[2];
  const float* iemb = (const float*)d_in[3];
  const float* linw = (const float*)d_in[4];
  const float* linb = (const float*)d_in[5];
  const float* K    = (const float*)d_in[6];
  const float* W1   = (const float*)d_in[7];
  const float* b1   = (const float*)d_in[8];
  const float* W2   = (const float*)d_in[9];
  const float* b2   = (const float*)d_in[10];
  const float* W3   = (const float*)d_in[11];
  const float* b3   = (const float*)d_in[12];
  const float* W4   = (const float*)d_in[13];
  const float* b4   = (const float*)d_in[14];
  const float* W5   = (const float*)d_in[15];
  const float* b5   = (const float*)d_in[16];

  char* w = (char*)d_ws;
  float* S = (float*)w;
  unsigned short* Kt  = (unsigned short*)(w + 512);
  unsigned short* W1t = (unsigned short*)(w + 33280);
  unsigned short* W2t = (unsigned short*)(w + 90624);
  unsigned short* W3t = (unsigned short*)(w + 205312);
  unsigned short* W4t = (unsigned short*)(w + 320000);
  float* out = (float*)d_out;

  dfm_prep<<<736, 256, 0, stream>>>(K, W1, W2, W3, W4, S, Kt, W1t, W2t, W3t, W4t);
  dfm_main<<<BATCH / BM, 256, 0, stream>>>(uidx, iidx, uemb, iemb, linw, linb,
                                           b1, b2, b3, b4, W5, b5,
                                           S, Kt, W2t, W3t, W4t, out);
}

// Round 6
// 289.323 us; speedup vs baseline: 2.6359x; 1.1290x over previous
//
#include <hip/hip_runtime.h>

#define HASH_BINS 100000
#define EMBD 64
#define BATCH 262144
#define BM 64
#define SA 264  // act buffer A stride (bf16): 528B rows, 16B-aligned, 2-way bank alias (free)
#define SB 232  // act buffer B stride (bf16): 464B rows, 16B-aligned, 2-way bank alias (free)

typedef __attribute__((ext_vector_type(8))) short short8;
typedef __attribute__((ext_vector_type(4))) float floatx4;
typedef __attribute__((ext_vector_type(4))) unsigned short ushortx4;

static __device__ __forceinline__ unsigned short f2bf(float f) {
  unsigned u = __builtin_bit_cast(unsigned, f);
  u += 0x7fff + ((u >> 16) & 1);  // round-to-nearest-even
  return (unsigned short)(u >> 16);
}
static __device__ __forceinline__ float bf2f(unsigned short b) {
  return __builtin_bit_cast(float, ((unsigned)b) << 16);
}

// ---------------- prep: build bf16 transposed/padded weights in ws ----------------
// ws layout (bytes):
//   0      : S   fp32 [128]            (rowsum of cross_k^2)
//   512    : Kt  bf16 [128][128]       (cross_k transposed)   } contiguous => combined
//   33280  : W1t bf16 [224][128]       (W1 transposed, N-pad) } [352][128] matrix
//   90624  : W2t bf16 [256][224]       (K-pad 200->224)
//   205312 : W3t bf16 [224][256]       (N-pad 200->224)
//   320000 : W4t bf16 [128][224]       (K-pad 200->224)
__global__ void dfm_prep(const float* __restrict__ K, const float* __restrict__ W1,
                         const float* __restrict__ W2, const float* __restrict__ W3,
                         const float* __restrict__ W4,
                         float* __restrict__ S, unsigned short* __restrict__ Kt,
                         unsigned short* __restrict__ W1t, unsigned short* __restrict__ W2t,
                         unsigned short* __restrict__ W3t, unsigned short* __restrict__ W4t)
{
  int idx = blockIdx.x * 256 + threadIdx.x;
  if (idx < 128) {
    float s = 0.f;
    for (int j = 0; j < 128; j++) { float v = K[idx * 128 + j]; s += v * v; }
    S[idx] = s;
  }
  int i = idx;
  if (i < 16384) {                        // Kt[n][k] = K[k][n]; i over source K
    int k = i >> 7, n = i & 127;
    Kt[n * 128 + k] = f2bf(K[i]);
  } else if ((i -= 16384) < 25600) {      // W1t[n][k] = W1[k][n]; i over source W1 [128][200]
    int k = i / 200, n = i - k * 200;
    W1t[n * 128 + k] = f2bf(W1[i]);
  } else if ((i -= 25600) < 3072) {       // W1t zero rows n in [200,224)
    int n = 200 + (i >> 7), k = i & 127;
    W1t[n * 128 + k] = 0;
  } else if ((i -= 3072) < 51200) {       // W2t[n][k] = W2[k][n]; source W2 [200][256]
    int k = i >> 8, n = i & 255;
    W2t[n * 224 + k] = f2bf(W2[i]);
  } else if ((i -= 51200) < 6144) {       // W2t zero k in [200,224), n in [0,256)
    int n = i / 24, k = 200 + (i - n * 24);
    W2t[n * 224 + k] = 0;
  } else if ((i -= 6144) < 51200) {       // W3t[n][k] = W3[k][n]; source W3 [256][200]
    int k = i / 200, n = i - k * 200;
    W3t[n * 256 + k] = f2bf(W3[i]);
  } else if ((i -= 51200) < 6144) {       // W3t zero rows n in [200,224)
    int n = 200 + (i >> 8), k = i & 255;
    W3t[n * 256 + k] = 0;
  } else if ((i -= 6144) < 25600) {       // W4t[n][k] = W4[k][n]; source W4 [200][128]
    int k = i >> 7, n = i & 127;
    W4t[n * 224 + k] = f2bf(W4[i]);
  } else if ((i -= 25600) < 3072) {       // W4t zero k in [200,224), n in [0,128)
    int n = i / 24, k = 200 + (i - n * 24);
    W4t[n * 224 + k] = 0;
  }
}

// ---- MFMA pass: CH n-tiles x 4 row-tiles (all 64 rows), K=KP ----
// Each weight fragment is read by exactly ONE wave per block (N-partition).
template <int KP, int CH>
static __device__ __forceinline__ void mfma_pass(const unsigned short* __restrict__ wt,
                                                 int rowOff, const unsigned short* actIn,
                                                 int sin, int m, int qd, floatx4* acc)
{
#pragma unroll
  for (int i = 0; i < CH * 4; i++) acc[i] = {0.f, 0.f, 0.f, 0.f};
#pragma unroll
  for (int ks = 0; ks < KP / 32; ks++) {
    short8 a[4];
#pragma unroll
    for (int rt = 0; rt < 4; rt++)
      a[rt] = *(const short8*)&actIn[(rt * 16 + m) * sin + ks * 32 + qd * 8];
#pragma unroll
    for (int n = 0; n < CH; n++) {
      short8 b = *(const short8*)&wt[(rowOff + n * 16 + m) * KP + ks * 32 + qd * 8];
#pragma unroll
      for (int rt = 0; rt < 4; rt++)
        acc[n * 4 + rt] = __builtin_amdgcn_mfma_f32_16x16x32_bf16(a[rt], b, acc[n * 4 + rt], 0, 0, 0);
    }
  }
}

template <int CH>
static __device__ __forceinline__ void epilogue_relu(const float* __restrict__ bias,
                                                     int colBase, int nreal,
                                                     unsigned short* actOut, int sout,
                                                     int m, int qd, const floatx4* acc)
{
#pragma unroll
  for (int n = 0; n < CH; n++) {
    int col = colBase + n * 16 + m;
    float bv = (col < nreal) ? bias[col] : 0.f;
#pragma unroll
    for (int rt = 0; rt < 4; rt++)
#pragma unroll
      for (int i = 0; i < 4; i++) {
        float v = fmaxf(acc[n * 4 + rt][i] + bv, 0.f);  // padded cols: 0+0 -> 0
        actOut[(rt * 16 + qd * 4 + i) * sout + col] = f2bf(v);
      }
  }
}

// ---------------- fused main kernel ----------------
// 512 threads = 8 waves per block; each wave computes ALL 64 rows x 1/8 of the
// output tiles. LDS unchanged (66 KB -> 2 blocks/CU) but 16 waves/CU now.
__global__ __launch_bounds__(512)
void dfm_main(const int* __restrict__ uidx, const int* __restrict__ iidx,
              const float* __restrict__ uemb, const float* __restrict__ iemb,
              const float* __restrict__ linw, const float* __restrict__ linb,
              const float* __restrict__ b1, const float* __restrict__ b2,
              const float* __restrict__ b3, const float* __restrict__ b4,
              const float* __restrict__ W5, const float* __restrict__ b5,
              const float* __restrict__ S, const unsigned short* __restrict__ Wc,
              const unsigned short* __restrict__ W2t, const unsigned short* __restrict__ W3t,
              const unsigned short* __restrict__ W4t,
              float* __restrict__ out)
{
  __shared__ unsigned short actA[BM * SA];
  __shared__ unsigned short actB[BM * SB];
  __shared__ float crosspart[4][BM];
  __shared__ float part[BM][8];
  __shared__ float linrow[BM];

  const int t = threadIdx.x;
  const int lane = t & 63, wave = t >> 6;
  const int m = lane & 15, qd = lane >> 4;
  const int r = t >> 3, c = t & 7;  // gather/final mapping: 8 threads per row

  // ---- gather + linear + q-partials (q = sum x^2 * rowsum(K^2)) ----
  {
    int g = blockIdx.x * BM + r;
    int u = uidx[g], it = iidx[g];
    const float* up = uemb + (long)u * EMBD + c * 8;
    const float* ip = iemb + (long)it * EMBD + c * 8;
    float qp = 0.f;
#pragma unroll
    for (int j = 0; j < 8; j += 4) {
      float4 f = *(const float4*)(up + j);
      int col = c * 8 + j;
      float4 sv = *(const float4*)(S + col);
      ushortx4 h = {f2bf(f.x), f2bf(f.y), f2bf(f.z), f2bf(f.w)};
      *(ushortx4*)&actA[r * SA + col] = h;
      qp += f.x * f.x * sv.x + f.y * f.y * sv.y + f.z * f.z * sv.z + f.w * f.w * sv.w;
    }
#pragma unroll
    for (int j = 0; j < 8; j += 4) {
      float4 f = *(const float4*)(ip + j);
      int col = 64 + c * 8 + j;
      float4 sv = *(const float4*)(S + col);
      ushortx4 h = {f2bf(f.x), f2bf(f.y), f2bf(f.z), f2bf(f.w)};
      *(ushortx4*)&actA[r * SA + col] = h;
      qp += f.x * f.x * sv.x + f.y * f.y * sv.y + f.z * f.z * sv.z + f.w * f.w * sv.w;
    }
    part[r][c] = qp;
    if (c == 0) linrow[r] = linw[u] + linw[HASH_BINS + it] + linb[0];
  }
  __syncthreads();  // B1: emb in actA

  // ---- fused layer (K=128, reads actA): cross (8 tiles) + L1 (14 tiles) -> actB ----
  // waves 0-3: 2 cross tiles + 1 L1 tile; wave4: L1 {4,5,6}; wave5: L1 {7,8,9};
  // wave6: L1 {10,11}; wave7: L1 {12,13}.
  if (wave < 4) {
    floatx4 acc[8];
    mfma_pass<128, 2>(Wc, (2 * wave) * 16, actA, SA, m, qd, acc);
    float s[4][4];
#pragma unroll
    for (int rt = 0; rt < 4; rt++)
#pragma unroll
      for (int i = 0; i < 4; i++)
        s[rt][i] = acc[rt][i] * acc[rt][i] + acc[4 + rt][i] * acc[4 + rt][i];
#pragma unroll
    for (int mask = 1; mask < 16; mask <<= 1)
#pragma unroll
      for (int rt = 0; rt < 4; rt++)
#pragma unroll
        for (int i = 0; i < 4; i++)
          s[rt][i] += __shfl_xor(s[rt][i], mask, 64);
    if (m == 0)
#pragma unroll
      for (int rt = 0; rt < 4; rt++)
#pragma unroll
        for (int i = 0; i < 4; i++)
          crosspart[wave][rt * 16 + qd * 4 + i] = s[rt][i];
    floatx4 acc2[4];
    mfma_pass<128, 1>(Wc, 128 + wave * 16, actA, SA, m, qd, acc2);
    epilogue_relu<1>(b1, wave * 16, 200, actB, SB, m, qd, acc2);
  } else if (wave < 6) {
    int s0 = 4 + (wave - 4) * 3;  // 4 or 7
    floatx4 acc[12];
    mfma_pass<128, 3>(Wc, 128 + s0 * 16, actA, SA, m, qd, acc);
    epilogue_relu<3>(b1, s0 * 16, 200, actB, SB, m, qd, acc);
  } else {
    int s0 = 10 + (wave - 6) * 2;  // 10 or 12
    floatx4 acc[8];
    mfma_pass<128, 2>(Wc, 128 + s0 * 16, actA, SA, m, qd, acc);
    epilogue_relu<2>(b1, s0 * 16, 200, actB, SB, m, qd, acc);
  }
  __syncthreads();  // B2: L1 out (224 cols, zero-padded) in actB

  // ---- W2: K=224, actB -> actA, 16 tiles, 2 per wave ----
  {
    floatx4 acc[8];
    mfma_pass<224, 2>(W2t, wave * 2 * 16, actB, SB, m, qd, acc);
    epilogue_relu<2>(b2, wave * 2 * 16, 256, actA, SA, m, qd, acc);
  }
  __syncthreads();  // B3: W2 out (256) in actA

  // ---- W3: K=256, actA -> actB, 14 tiles: waves 0-5 get 2, waves 6-7 get 1 ----
  if (wave < 6) {
    floatx4 acc[8];
    mfma_pass<256, 2>(W3t, wave * 2 * 16, actA, SA, m, qd, acc);
    epilogue_relu<2>(b3, wave * 2 * 16, 200, actB, SB, m, qd, acc);
  } else {
    int s0 = 12 + (wave - 6);
    floatx4 acc[4];
    mfma_pass<256, 1>(W3t, s0 * 16, actA, SA, m, qd, acc);
    epilogue_relu<1>(b3, s0 * 16, 200, actB, SB, m, qd, acc);
  }
  __syncthreads();  // B4: W3 out (224, zero-padded) in actB

  // ---- W4: K=224, actB -> actA, 8 tiles, 1 per wave ----
  {
    floatx4 acc[4];
    mfma_pass<224, 1>(W4t, wave * 16, actB, SB, m, qd, acc);
    epilogue_relu<1>(b4, wave * 16, 128, actA, SA, m, qd, acc);
  }
  __syncthreads();  // B5: W4 out (128) in actA

  // ---- final: W5 dot + cross combine + sigmoid ----
  {
    float qp = part[r][c];  // q-partial from gather phase (same thread wrote it)
    float d = 0.f;
    const unsigned short* ap = &actA[r * SA + c * 16];
#pragma unroll
    for (int j = 0; j < 2; j++) {
      short8 h = *(const short8*)(ap + j * 8);
      float4 w0 = *(const float4*)(W5 + c * 16 + j * 8);
      float4 w1 = *(const float4*)(W5 + c * 16 + j * 8 + 4);
      d += bf2f((unsigned short)h[0]) * w0.x + bf2f((unsigned short)h[1]) * w0.y +
           bf2f((unsigned short)h[2]) * w0.z + bf2f((unsigned short)h[3]) * w0.w +
           bf2f((unsigned short)h[4]) * w1.x + bf2f((unsigned short)h[5]) * w1.y +
           bf2f((unsigned short)h[6]) * w1.z + bf2f((unsigned short)h[7]) * w1.w;
    }
    const float inv = 0.5f / 128.f;
    part[r][c] = d - inv * qp;  // dnn partial minus q share of cross
    __syncthreads();
    if (c == 0) {
      float xk2 = crosspart[0][r] + crosspart[1][r] + crosspart[2][r] + crosspart[3][r];
      float dnn = part[r][0] + part[r][1] + part[r][2] + part[r][3] +
                  part[r][4] + part[r][5] + part[r][6] + part[r][7];
      float logit = linrow[r] + inv * xk2 + dnn + b5[0];
      out[blockIdx.x * BM + r] = 1.f / (1.f + expf(-logit));
    }
  }
}

extern "C" void kernel_launch(void* const* d_in, const int* in_sizes, int n_in,
                              void* d_out, int out_size, void* d_ws, size_t ws_size,
                              hipStream_t stream)
{
  const int*   uidx = (const int*)d_in[0];
  const int*   iidx = (const int*)d_in[1];
  const float* uemb = (const float*)d_in[2];
  const float* iemb = (const float*)d_in[3];
  const float* linw = (const float*)d_in[4];
  const float* linb = (const float*)d_in[5];
  const float* K    = (const float*)d_in[6];
  const float* W1   = (const float*)d_in[7];
  const float* b1   = (const float*)d_in[8];
  const float* W2   = (const float*)d_in[9];
  const float* b2   = (const float*)d_in[10];
  const float* W3   = (const float*)d_in[11];
  const float* b3   = (const float*)d_in[12];
  const float* W4   = (const float*)d_in[13];
  const float* b4   = (const float*)d_in[14];
  const float* W5   = (const float*)d_in[15];
  const float* b5   = (const float*)d_in[16];

  char* w = (char*)d_ws;
  float* S = (float*)w;
  unsigned short* Kt  = (unsigned short*)(w + 512);
  unsigned short* W1t = (unsigned short*)(w + 33280);
  unsigned short* W2t = (unsigned short*)(w + 90624);
  unsigned short* W3t = (unsigned short*)(w + 205312);
  unsigned short* W4t = (unsigned short*)(w + 320000);
  float* out = (float*)d_out;

  dfm_prep<<<736, 256, 0, stream>>>(K, W1, W2, W3, W4, S, Kt, W1t, W2t, W3t, W4t);
  dfm_main<<<BATCH / BM, 512, 0, stream>>>(uidx, iidx, uemb, iemb, linw, linb,
                                           b1, b2, b3, b4, W5, b5,
                                           S, Kt, W2t, W3t, W4t, out);
}